// Round 5
// baseline (2608.451 us; speedup 1.0000x reference)
//
#include <hip/hip_runtime.h>

typedef unsigned short u16;
typedef unsigned int u32;
typedef short bf16x8 __attribute__((ext_vector_type(8)));
typedef float f32x4 __attribute__((ext_vector_type(4)));
typedef u32 u32x4 __attribute__((ext_vector_type(4)));

#define TOKENS 16384   // B*N = 16*1024
#define CDIM 768
#define NEXP 8

__device__ __forceinline__ float b2f(u16 u) {
  return __uint_as_float(((u32)u) << 16);
}
__device__ __forceinline__ u16 f2b(float f) {
  u32 u = __float_as_uint(f);
  return (u16)((u + 0x7fffu + ((u >> 16) & 1u)) >> 16);
}
__device__ __forceinline__ f32x4 mfma16(bf16x8 a, bf16x8 b, f32x4 c) {
  return __builtin_amdgcn_mfma_f32_16x16x32_bf16(a, b, c, 0, 0, 0);
}

// ---------------------------------------------------------------- transpose
// in: K x N fp32 row-major -> out: N x K bf16 row-major. batch via blockIdx.z.
__global__ __launch_bounds__(256) void transpose_f32_bf16(
    const float* __restrict__ in, u16* __restrict__ out, int K, int N) {
  __shared__ u16 tile[64][65];
  const int z = blockIdx.z;
  in += (size_t)z * K * N;
  out += (size_t)z * K * N;
  const int n0 = blockIdx.x * 64, k0 = blockIdx.y * 64;
#pragma unroll
  for (int i = 0; i < 16; i++) {
    const int s = threadIdx.x + i * 256;
    const int r = s >> 6, c = s & 63;
    tile[r][c] = f2b(in[(size_t)(k0 + r) * N + n0 + c]);
  }
  __syncthreads();
#pragma unroll
  for (int i = 0; i < 16; i++) {
    const int s = threadIdx.x + i * 256;
    const int r = s >> 6, c = s & 63;
    out[(size_t)(n0 + r) * K + k0 + c] = tile[c][r];
  }
}

// ---------------------------------------------------------------- layernorm
// one wave per row of 768; fp32 in; out fp32 (decision path) or bf16 (experts).
template <bool BF16OUT>
__global__ __launch_bounds__(256) void ln_rows(const float* __restrict__ in,
                                               const float* __restrict__ g,
                                               const float* __restrict__ bt,
                                               void* __restrict__ out) {
  const int row = blockIdx.x * 4 + (threadIdx.x >> 6);
  const int lane = threadIdx.x & 63;
  const size_t base = (size_t)row * CDIM;
  float v[12];
  float s = 0.f, ss = 0.f;
#pragma unroll
  for (int j = 0; j < 12; j++) {
    const int idx = lane + j * 64;
    v[j] = in[base + idx];
    s += v[j];
    ss += v[j] * v[j];
  }
#pragma unroll
  for (int m = 1; m < 64; m <<= 1) {
    s += __shfl_xor(s, m);
    ss += __shfl_xor(ss, m);
  }
  const float mean = s * (1.f / CDIM);
  const float var = ss * (1.f / CDIM) - mean * mean;
  const float rs = rsqrtf(var + 1e-5f);
#pragma unroll
  for (int j = 0; j < 12; j++) {
    const int idx = lane + j * 64;
    const float y = (v[j] - mean) * rs * g[idx] + bt[idx];
    if (BF16OUT)
      ((u16*)out)[base + idx] = f2b(y);
    else
      ((float*)out)[base + idx] = y;
  }
}

// ---------------------------------------------------------------- fp32 GEMM
// C[M,N] = A[M,K] * B[K,N], all fp32. 128x128 tile, BK=16, 256 threads,
// 8x8 micro-tile per thread (split 2x 4-row / 2x 4-col groups).
// EPI 0: plain store. EPI 1: C = acc + bias[col] + xres[row,col].
template <int EPI>
__global__ __launch_bounds__(256) void gemm_f32(
    const float* __restrict__ A, const float* __restrict__ B,
    float* __restrict__ C, int M, int N, int K, const float* __restrict__ bias,
    const float* __restrict__ xres) {
  __shared__ float As[16][132];  // [k][m], pad->2-way max
  __shared__ float Bs[16][128];  // [k][n]
  const int tid = threadIdx.x;
  const int ty = tid >> 4, tx = tid & 15;
  const int m0 = blockIdx.y * 128, n0 = blockIdx.x * 128;
  float acc[8][8];
#pragma unroll
  for (int i = 0; i < 8; i++)
#pragma unroll
    for (int j = 0; j < 8; j++) acc[i][j] = 0.f;
  const int ar = tid >> 2, ac = (tid & 3) * 4;
  const int br = tid >> 5, bc = (tid & 31) * 4;
  for (int k0 = 0; k0 < K; k0 += 16) {
    __syncthreads();
#pragma unroll
    for (int p = 0; p < 2; p++) {
      const int r = ar + p * 64;
      const float4 av = *(const float4*)(A + (size_t)(m0 + r) * K + k0 + ac);
      As[ac + 0][r] = av.x;
      As[ac + 1][r] = av.y;
      As[ac + 2][r] = av.z;
      As[ac + 3][r] = av.w;
      const int rb = br + p * 8;
      *(float4*)(&Bs[rb][bc]) =
          *(const float4*)(B + (size_t)(k0 + rb) * N + n0 + bc);
    }
    __syncthreads();
#pragma unroll
    for (int kk = 0; kk < 16; kk++) {
      float a[8], b[8];
      *(float4*)&a[0] = *(const float4*)(&As[kk][ty * 4]);
      *(float4*)&a[4] = *(const float4*)(&As[kk][64 + ty * 4]);
      *(float4*)&b[0] = *(const float4*)(&Bs[kk][tx * 4]);
      *(float4*)&b[4] = *(const float4*)(&Bs[kk][64 + tx * 4]);
#pragma unroll
      for (int i = 0; i < 8; i++)
#pragma unroll
        for (int j = 0; j < 8; j++) acc[i][j] += a[i] * b[j];
    }
  }
#pragma unroll
  for (int i = 0; i < 8; i++) {
    const int mrow = m0 + ((i < 4) ? (ty * 4 + i) : (64 + ty * 4 + i - 4));
#pragma unroll
    for (int jh = 0; jh < 2; jh++) {
      const int col = n0 + jh * 64 + tx * 4;
      float4 v;
      v.x = acc[i][jh * 4 + 0];
      v.y = acc[i][jh * 4 + 1];
      v.z = acc[i][jh * 4 + 2];
      v.w = acc[i][jh * 4 + 3];
      if (EPI == 1) {
        const size_t rb = (size_t)mrow * N + col;
        v.x += bias[col + 0] + xres[rb + 0];
        v.y += bias[col + 1] + xres[rb + 1];
        v.z += bias[col + 2] + xres[rb + 2];
        v.w += bias[col + 3] + xres[rb + 3];
      }
      *(float4*)(&C[(size_t)mrow * N + col]) = v;
    }
  }
}

// ---------------------------------------------------------------- fp32 attn
// block = (qtile 64, head, local-batch); 256 threads = 16x16, 4x4 micro.
// Flash online softmax, all fp32. qkvf holds a 4096-token quarter; qb is the
// quarter index (global batch = qb*4 + blockIdx.z).
// LDS: Qs[q][d], Ks[k][(d+k)&63] (rotated, conflict-free), Vs[k][d], Ps[q][k]
// = 4 x 16 KB = 64 KB exactly.
__global__ __launch_bounds__(256) void attn_f32(const float* __restrict__ qkvf,
                                                float* __restrict__ o, int qb) {
  __shared__ float Qs[64 * 64];
  __shared__ float Ks[64 * 64];
  __shared__ float Vs[64 * 64];
  __shared__ float Ps[64 * 64];
  const int bz = blockIdx.z, h = blockIdx.y, qt = blockIdx.x;
  const int tid = threadIdx.x;
  const int ty = tid >> 4, tx = tid & 15;
  const int sr = tid >> 4;
  const int sd = (tid & 15) * 4;
  const int gtok = (qb * 4 + bz) * 1024 + qt * 64;
#pragma unroll
  for (int p = 0; p < 4; p++) {
    const int r = sr + p * 16;
    *(float4*)(&Qs[r * 64 + sd]) = *(const float4*)(
        qkvf + (size_t)(bz * 1024 + qt * 64 + r) * 2304 + h * 64 + sd);
  }
  float mi[4], li[4], oA[4][4];
#pragma unroll
  for (int i = 0; i < 4; i++) {
    mi[i] = -1e30f;
    li[i] = 0.f;
#pragma unroll
    for (int j = 0; j < 4; j++) oA[i][j] = 0.f;
  }

  for (int kt = 0; kt < 16; kt++) {
    __syncthreads();
#pragma unroll
    for (int p = 0; p < 4; p++) {
      const int r = sr + p * 16;
      const size_t tb = (size_t)(bz * 1024 + kt * 64 + r) * 2304 + h * 64 + sd;
      const float4 kv = *(const float4*)(qkvf + tb + 768);
      Ks[r * 64 + ((sd + 0 + r) & 63)] = kv.x;
      Ks[r * 64 + ((sd + 1 + r) & 63)] = kv.y;
      Ks[r * 64 + ((sd + 2 + r) & 63)] = kv.z;
      Ks[r * 64 + ((sd + 3 + r) & 63)] = kv.w;
      *(float4*)(&Vs[r * 64 + sd]) = *(const float4*)(qkvf + tb + 1536);
    }
    __syncthreads();
    float s[4][4];
#pragma unroll
    for (int i = 0; i < 4; i++)
#pragma unroll
      for (int j = 0; j < 4; j++) s[i][j] = 0.f;
    for (int d4 = 0; d4 < 64; d4 += 4) {
      float4 a4[4];
#pragma unroll
      for (int i = 0; i < 4; i++)
        a4[i] = *(const float4*)(&Qs[(ty * 4 + i) * 64 + d4]);
#pragma unroll
      for (int dd = 0; dd < 4; dd++) {
        const int d = d4 + dd;
        float bv[4];
#pragma unroll
        for (int j = 0; j < 4; j++) {
          const int k = tx * 4 + j;
          bv[j] = Ks[k * 64 + ((d + k) & 63)];
        }
#pragma unroll
        for (int i = 0; i < 4; i++) {
          const float av = (dd == 0)   ? a4[i].x
                           : (dd == 1) ? a4[i].y
                           : (dd == 2) ? a4[i].z
                                       : a4[i].w;
#pragma unroll
          for (int j = 0; j < 4; j++) s[i][j] += av * bv[j];
        }
      }
    }
#pragma unroll
    for (int i = 0; i < 4; i++) {
      float mx = -1e30f;
#pragma unroll
      for (int j = 0; j < 4; j++) {
        s[i][j] *= 0.125f;  // Dh^-0.5
        mx = fmaxf(mx, s[i][j]);
      }
      mx = fmaxf(mx, __shfl_xor(mx, 1));
      mx = fmaxf(mx, __shfl_xor(mx, 2));
      mx = fmaxf(mx, __shfl_xor(mx, 4));
      mx = fmaxf(mx, __shfl_xor(mx, 8));
      const float mnew = fmaxf(mi[i], mx);
      const float alpha = expf(mi[i] - mnew);
      float ps = 0.f;
#pragma unroll
      for (int j = 0; j < 4; j++) {
        s[i][j] = expf(s[i][j] - mnew);
        ps += s[i][j];
      }
      ps += __shfl_xor(ps, 1);
      ps += __shfl_xor(ps, 2);
      ps += __shfl_xor(ps, 4);
      ps += __shfl_xor(ps, 8);
      li[i] = li[i] * alpha + ps;
      mi[i] = mnew;
#pragma unroll
      for (int j = 0; j < 4; j++) oA[i][j] *= alpha;
#pragma unroll
      for (int j = 0; j < 4; j++)
        Ps[(ty * 4 + i) * 64 + tx * 4 + j] = s[i][j];
    }
    __syncthreads();
    for (int k4 = 0; k4 < 64; k4 += 4) {
      float4 p4[4];
#pragma unroll
      for (int i = 0; i < 4; i++)
        p4[i] = *(const float4*)(&Ps[(ty * 4 + i) * 64 + k4]);
#pragma unroll
      for (int kk = 0; kk < 4; kk++) {
        const float4 vv = *(const float4*)(&Vs[(k4 + kk) * 64 + tx * 4]);
#pragma unroll
        for (int i = 0; i < 4; i++) {
          const float pv = (kk == 0)   ? p4[i].x
                           : (kk == 1) ? p4[i].y
                           : (kk == 2) ? p4[i].z
                                       : p4[i].w;
          oA[i][0] += pv * vv.x;
          oA[i][1] += pv * vv.y;
          oA[i][2] += pv * vv.z;
          oA[i][3] += pv * vv.w;
        }
      }
    }
  }
#pragma unroll
  for (int i = 0; i < 4; i++) {
    const float inv = 1.f / li[i];
    float4 v;
    v.x = oA[i][0] * inv;
    v.y = oA[i][1] * inv;
    v.z = oA[i][2] * inv;
    v.w = oA[i][3] * inv;
    *(float4*)(&o[(size_t)(gtok + ty * 4 + i) * 768 + h * 64 + tx * 4]) = v;
  }
}

// ---------------------------------------------------------------- bf16 GEMM
// expert arm only (MODE 2): gathered rows via tokList (expert = blockIdx.z),
// scatter atomicAdd((acc+bias_e)*w) into fp32 C by token.
template <int MODE>
__global__ __launch_bounds__(256) void gemm_bt(
    const u16* __restrict__ A, const u16* __restrict__ Bt,
    void* __restrict__ Cout, int M, int N, int K,
    const float* __restrict__ bias, const float* __restrict__ xres,
    const int* __restrict__ counts, const int* __restrict__ tokList,
    const float* __restrict__ wgtList) {
  __shared__ u16 As[128 * 64];
  __shared__ u16 Bs[128 * 64];
  const int tid = threadIdx.x;
  const int lane = tid & 63, wv = tid >> 6;
  const int wr = wv >> 1, wc = wv & 1;
  const int lm = lane & 15, lq = lane >> 4;
  const int m0 = blockIdx.y * 128, n0 = blockIdx.x * 128;
  int cnt = M;
  const u16* Bte = Bt;
  const int* tokl = nullptr;
  const float* wl = nullptr;
  const float* biasE = bias;
  if (MODE == 2) {
    const int e = blockIdx.z;
    cnt = counts[e];
    if (m0 >= cnt) return;
    Bte = Bt + (size_t)e * N * K;
    tokl = tokList + e * TOKENS;
    wl = wgtList + e * TOKENS;
    biasE = bias + e * N;
  }
  f32x4 acc[4][4];
  const f32x4 z4 = {0.f, 0.f, 0.f, 0.f};
#pragma unroll
  for (int i = 0; i < 4; i++)
#pragma unroll
    for (int j = 0; j < 4; j++) acc[i][j] = z4;

  for (int k0 = 0; k0 < K; k0 += 64) {
    __syncthreads();
#pragma unroll
    for (int i = 0; i < 4; i++) {
      const int s = tid + i * 256;
      const int r = s >> 3, g = s & 7;
      u32x4 av;
      if (MODE == 2) {
        const int row = m0 + r;
        if (row < cnt) {
          av = *(const u32x4*)(A + (size_t)tokl[row] * K + k0 + g * 8);
        } else {
          av = (u32x4){0u, 0u, 0u, 0u};
        }
      } else {
        av = *(const u32x4*)(A + (size_t)(m0 + r) * K + k0 + g * 8);
      }
      *(u32x4*)(&As[r * 64 + ((g ^ (r & 7)) << 3)]) = av;
      const u32x4 bv = *(const u32x4*)(Bte + (size_t)(n0 + r) * K + k0 + g * 8);
      *(u32x4*)(&Bs[r * 64 + ((g ^ (r & 7)) << 3)]) = bv;
    }
    __syncthreads();
#pragma unroll
    for (int kx = 0; kx < 8; kx += 4) {
      bf16x8 af[4], bfv[4];
#pragma unroll
      for (int i = 0; i < 4; i++) {
        const int ra = wr * 64 + i * 16 + lm;
        af[i] = *(const bf16x8*)(&As[ra * 64 + (((ra & 7) ^ (kx + lq)) << 3)]);
        const int rb = wc * 64 + i * 16 + lm;
        bfv[i] = *(const bf16x8*)(&Bs[rb * 64 + (((rb & 7) ^ (kx + lq)) << 3)]);
      }
#pragma unroll
      for (int i = 0; i < 4; i++)
#pragma unroll
        for (int j = 0; j < 4; j++)
          acc[i][j] = mfma16(af[i], bfv[j], acc[i][j]);
    }
  }

  {
    float* C = (float*)Cout;
#pragma unroll
    for (int i = 0; i < 4; i++)
#pragma unroll
      for (int r = 0; r < 4; r++) {
        const int rowi = m0 + wr * 64 + i * 16 + lq * 4 + r;
        if (rowi < cnt) {
          const int tok = tokl[rowi];
          const float w = wl[rowi];
#pragma unroll
          for (int j = 0; j < 4; j++) {
            const int col = n0 + wc * 64 + j * 16 + lm;
            const float val = (acc[i][j][r] + biasE[col]) * w;
            atomicAdd(&C[(size_t)tok * N + col], val);
          }
        }
      }
  }
}

// ---------------------------------------------------------------- router
// one wave per token, ALL-FP32: recompute LN2 from x2 (fp32), logits =
// LN_E(h2f @ route_w + route_b); softmax + noise/8; top-2; softmax of 2.
__global__ __launch_bounds__(256) void router_kernel(
    const float* __restrict__ x2, const float* __restrict__ g2,
    const float* __restrict__ b2, const float* __restrict__ rw,
    const float* __restrict__ rb, const float* __restrict__ rlng,
    const float* __restrict__ rlnb, const float* __restrict__ noise,
    int* __restrict__ eidx, float* __restrict__ ewgt) {
  const int token = blockIdx.x * 4 + (threadIdx.x >> 6);
  const int lane = threadIdx.x & 63;
  const size_t base = (size_t)token * CDIM;
  float v[12];
  float s = 0.f, ss = 0.f;
#pragma unroll
  for (int j = 0; j < 12; j++) {
    const int idx = lane + j * 64;
    v[j] = x2[base + idx];
    s += v[j];
    ss += v[j] * v[j];
  }
#pragma unroll
  for (int m = 1; m < 64; m <<= 1) {
    s += __shfl_xor(s, m);
    ss += __shfl_xor(ss, m);
  }
  const float mean = s * (1.f / CDIM);
  const float var = ss * (1.f / CDIM) - mean * mean;
  const float rs = rsqrtf(var + 1e-5f);

  float acc[8];
#pragma unroll
  for (int e = 0; e < 8; e++) acc[e] = 0.f;
#pragma unroll
  for (int j = 0; j < 12; j++) {
    const int d = lane + j * 64;
    const float hv = (v[j] - mean) * rs * g2[d] + b2[d];
    const f32x4 w0v = *(const f32x4*)(rw + (size_t)d * 8);
    const f32x4 w1v = *(const f32x4*)(rw + (size_t)d * 8 + 4);
#pragma unroll
    for (int e = 0; e < 4; e++) {
      acc[e] += hv * w0v[e];
      acc[e + 4] += hv * w1v[e];
    }
  }
#pragma unroll
  for (int m = 1; m < 64; m <<= 1)
#pragma unroll
    for (int e = 0; e < 8; e++) acc[e] += __shfl_xor(acc[e], m);

  float y[8];
  float emean = 0.f;
#pragma unroll
  for (int e = 0; e < 8; e++) {
    y[e] = acc[e] + rb[e];
    emean += y[e];
  }
  emean *= 0.125f;
  float evar = 0.f;
#pragma unroll
  for (int e = 0; e < 8; e++) {
    const float d = y[e] - emean;
    evar += d * d;
  }
  evar *= 0.125f;
  const float ers = rsqrtf(evar + 1e-5f);
  float lg[8];
  float mx = -1e30f;
#pragma unroll
  for (int e = 0; e < 8; e++) {
    lg[e] = (y[e] - emean) * ers * rlng[e] + rlnb[e];
    mx = fmaxf(mx, lg[e]);
  }
  float se = 0.f;
#pragma unroll
  for (int e = 0; e < 8; e++) {
    lg[e] = expf(lg[e] - mx);
    se += lg[e];
  }
  const float inv = 1.f / se;
  float r2[8];
#pragma unroll
  for (int e = 0; e < 8; e++)
    r2[e] = lg[e] * inv + noise[(size_t)token * 8 + e] * 0.125f;

  int e0 = 0;
  float v0 = r2[0];
#pragma unroll
  for (int e = 1; e < 8; e++)
    if (r2[e] > v0) {
      v0 = r2[e];
      e0 = e;
    }
  int e1 = -1;
  float v1 = -1e30f;
#pragma unroll
  for (int e = 0; e < 8; e++)
    if (e != e0 && r2[e] > v1) {
      v1 = r2[e];
      e1 = e;
    }
  const float w0 = 1.f / (1.f + expf(v1 - v0));
  if (lane == 0) {
    eidx[token * 2] = e0;
    eidx[token * 2 + 1] = e1;
    ewgt[token * 2] = w0;
    ewgt[token * 2 + 1] = 1.f - w0;
  }
}

// ---------------------------------------------------------------- lists
__global__ __launch_bounds__(256) void build_lists(
    const int* __restrict__ eidx, const float* __restrict__ ewgt,
    int* __restrict__ counts, int* __restrict__ tokL,
    float* __restrict__ wgtL) {
  const int e = blockIdx.x;
  __shared__ int cnt;
  if (threadIdx.x == 0) cnt = 0;
  __syncthreads();
  const int lane = threadIdx.x & 63;
  for (int t = threadIdx.x; t < TOKENS; t += 256) {
#pragma unroll
    for (int k = 0; k < 2; k++) {
      const bool match = (eidx[t * 2 + k] == e);
      const unsigned long long mb = __ballot(match);
      if (mb) {
        const int leader = __ffsll((unsigned long long)mb) - 1;
        int base = 0;
        if (lane == leader) base = atomicAdd(&cnt, __popcll(mb));
        base = __shfl(base, leader);
        if (match) {
          const int rank = __popcll(mb & ((1ull << lane) - 1ull));
          tokL[e * TOKENS + base + rank] = t;
          wgtL[e * TOKENS + base + rank] = ewgt[t * 2 + k];
        }
      }
    }
  }
  __syncthreads();
  if (threadIdx.x == 0) counts[e] = cnt;
}

// ---------------------------------------------------------------- copy
__global__ __launch_bounds__(256) void copy_f32(const float* __restrict__ in,
                                                float* __restrict__ out) {
  const int i = (blockIdx.x * 256 + threadIdx.x) * 4;
  *(float4*)(out + i) = *(const float4*)(in + i);
}

// ---------------------------------------------------------------- launch
extern "C" void kernel_launch(void* const* d_in, const int* in_sizes, int n_in,
                              void* d_out, int out_size, void* d_ws,
                              size_t ws_size, hipStream_t stream) {
  const float* x = (const float*)d_in[0];
  const float* noise = (const float*)d_in[1];
  const float* ln1_g = (const float*)d_in[2];
  const float* ln1_b = (const float*)d_in[3];
  const float* qkv_w = (const float*)d_in[4];
  const float* proj_w = (const float*)d_in[5];
  const float* proj_b = (const float*)d_in[6];
  const float* ln2_g = (const float*)d_in[7];
  const float* ln2_b = (const float*)d_in[8];
  const float* route_w = (const float*)d_in[9];
  const float* route_b = (const float*)d_in[10];
  const float* rln_g = (const float*)d_in[11];
  const float* rln_b = (const float*)d_in[12];
  const float* expert_w = (const float*)d_in[13];
  const float* expert_b = (const float*)d_in[14];

  char* ws = (char*)d_ws;
  // [0, 50331648)          x2f fp32 (residual + accumulation target)
  // [50331648, 88080384)   qkvf fp32 quarter (4096 tok x 2304); after attn is
  //                        done this region is reused for exp_wt + h2 + lists
  float* x2f = (float*)(ws);
  float* qkvf = (float*)(ws + 50331648);
  u16* exp_wt = (u16*)(ws + 50331648);        // 9437184 B (post-attn)
  u16* h2 = (u16*)(ws + 59768832);            // 25165824 B (post-attn)
  int* counts = (int*)(ws + 84934656);        // 256 B
  int* eidx = (int*)(ws + 84934912);          // 131072 B
  float* ewgt = (float*)(ws + 85065984);      // 131072 B
  int* tokL = (int*)(ws + 85197056);          // 524288 B
  float* wgtL = (float*)(ws + 85721344);      // 524288 B
  // h1f (post-LN1) and attention output o ping-pong through d_out (fp32),
  // quarter by quarter; the final copy overwrites d_out with x2f.
  float* h1f = (float*)d_out;

  const dim3 blk(256);
  ln_rows<false><<<dim3(4096), blk, 0, stream>>>(x, ln1_g, ln1_b, h1f);
  for (int q = 0; q < 4; q++) {
    gemm_f32<0><<<dim3(18, 32), blk, 0, stream>>>(
        h1f + (size_t)q * 4096 * 768, qkv_w, qkvf, 4096, 2304, 768, nullptr,
        nullptr);
    attn_f32<<<dim3(16, 12, 4), blk, 0, stream>>>(qkvf, h1f, q);
  }
  gemm_f32<1><<<dim3(6, 128), blk, 0, stream>>>(h1f, proj_w, x2f, 16384, 768,
                                                768, proj_b, x);
  ln_rows<true><<<dim3(4096), blk, 0, stream>>>(x2f, ln2_g, ln2_b, h2);
  transpose_f32_bf16<<<dim3(12, 12, 8), blk, 0, stream>>>(expert_w, exp_wt,
                                                          768, 768);
  router_kernel<<<dim3(4096), blk, 0, stream>>>(x2f, ln2_g, ln2_b, route_w,
                                                route_b, rln_g, rln_b, noise,
                                                eidx, ewgt);
  build_lists<<<dim3(8), blk, 0, stream>>>(eidx, ewgt, counts, tokL, wgtL);
  gemm_bt<2><<<dim3(6, 128, 8), blk, 0, stream>>>(
      h2, exp_wt, x2f, 16384, 768, 768, expert_b, nullptr, counts, tokL, wgtL);
  copy_f32<<<dim3(12288), blk, 0, stream>>>(x2f, (float*)d_out);
}

// Round 6
// 1188.419 us; speedup vs baseline: 2.1949x; 2.1949x over previous
//
#include <hip/hip_runtime.h>

typedef unsigned short u16;
typedef unsigned int u32;
typedef _Float16 f16;
typedef short bf16x8 __attribute__((ext_vector_type(8)));
typedef f16 f16x8 __attribute__((ext_vector_type(8)));
typedef float f32x4 __attribute__((ext_vector_type(4)));
typedef u32 u32x4 __attribute__((ext_vector_type(4)));

#define TOKENS 16384   // B*N = 16*1024
#define CDIM 768
#define NEXP 8

__device__ __forceinline__ float b2f(u16 u) {
  return __uint_as_float(((u32)u) << 16);
}
__device__ __forceinline__ u16 f2b(float f) {
  u32 u = __float_as_uint(f);
  return (u16)((u + 0x7fffu + ((u >> 16) & 1u)) >> 16);
}
__device__ __forceinline__ f32x4 mfma_bf(bf16x8 a, bf16x8 b, f32x4 c) {
  return __builtin_amdgcn_mfma_f32_16x16x32_bf16(a, b, c, 0, 0, 0);
}
__device__ __forceinline__ f32x4 mfma_h(f16x8 a, f16x8 b, f32x4 c) {
  return __builtin_amdgcn_mfma_f32_16x16x32_f16(a, b, c, 0, 0, 0);
}
// split 8 fp32 into f16 hi/lo planes (x = hi + lo, err ~2^-22|x|)
__device__ __forceinline__ void split8(const float* v, f16x8& h, f16x8& l) {
#pragma unroll
  for (int i = 0; i < 8; i++) {
    const f16 hh = (f16)v[i];
    h[i] = hh;
    l[i] = (f16)(v[i] - (float)hh);
  }
}

// -------------------------------------------------- transpose+split (f16)
// in: K x N fp32 -> oh/ol: N x K f16 hi/lo planes
__global__ __launch_bounds__(256) void transpose_split_f16(
    const float* __restrict__ in, f16* __restrict__ oh, f16* __restrict__ ol,
    int K, int N) {
  __shared__ float tile[64][65];
  const int n0 = blockIdx.x * 64, k0 = blockIdx.y * 64;
#pragma unroll
  for (int i = 0; i < 16; i++) {
    const int s = threadIdx.x + i * 256;
    const int r = s >> 6, c = s & 63;
    tile[r][c] = in[(size_t)(k0 + r) * N + n0 + c];
  }
  __syncthreads();
#pragma unroll
  for (int i = 0; i < 16; i++) {
    const int s = threadIdx.x + i * 256;
    const int r = s >> 6, c = s & 63;
    const float v = tile[c][r];
    const f16 h = (f16)v;
    oh[(size_t)(n0 + r) * K + k0 + c] = h;
    ol[(size_t)(n0 + r) * K + k0 + c] = (f16)(v - (float)h);
  }
}

// -------------------------------------------------- transpose (bf16, experts)
__global__ __launch_bounds__(256) void transpose_f32_bf16(
    const float* __restrict__ in, u16* __restrict__ out, int K, int N) {
  __shared__ u16 tile[64][65];
  const int z = blockIdx.z;
  in += (size_t)z * K * N;
  out += (size_t)z * K * N;
  const int n0 = blockIdx.x * 64, k0 = blockIdx.y * 64;
#pragma unroll
  for (int i = 0; i < 16; i++) {
    const int s = threadIdx.x + i * 256;
    const int r = s >> 6, c = s & 63;
    tile[r][c] = f2b(in[(size_t)(k0 + r) * N + n0 + c]);
  }
  __syncthreads();
#pragma unroll
  for (int i = 0; i < 16; i++) {
    const int s = threadIdx.x + i * 256;
    const int r = s >> 6, c = s & 63;
    out[(size_t)(n0 + r) * K + k0 + c] = tile[c][r];
  }
}

// -------------------------------------------------- layernorm
template <bool BF16OUT>
__global__ __launch_bounds__(256) void ln_rows(const float* __restrict__ in,
                                               const float* __restrict__ g,
                                               const float* __restrict__ bt,
                                               void* __restrict__ out) {
  const int row = blockIdx.x * 4 + (threadIdx.x >> 6);
  const int lane = threadIdx.x & 63;
  const size_t base = (size_t)row * CDIM;
  float v[12];
  float s = 0.f, ss = 0.f;
#pragma unroll
  for (int j = 0; j < 12; j++) {
    const int idx = lane + j * 64;
    v[j] = in[base + idx];
    s += v[j];
    ss += v[j] * v[j];
  }
#pragma unroll
  for (int m = 1; m < 64; m <<= 1) {
    s += __shfl_xor(s, m);
    ss += __shfl_xor(ss, m);
  }
  const float mean = s * (1.f / CDIM);
  const float var = ss * (1.f / CDIM) - mean * mean;
  const float rs = rsqrtf(var + 1e-5f);
#pragma unroll
  for (int j = 0; j < 12; j++) {
    const int idx = lane + j * 64;
    const float y = (v[j] - mean) * rs * g[idx] + bt[idx];
    if (BF16OUT)
      ((u16*)out)[base + idx] = f2b(y);
    else
      ((float*)out)[base + idx] = y;
  }
}

// -------------------------------------------------- f16-split GEMM
// C[M,N] = A[M,K](fp32, split in-kernel) * Bt[N,K](pre-split f16 hi/lo).
// 128x128 tile, BK=64, 4 waves 2x2, 16x16x32 f16 MFMA, 3 MFMAs per product
// (hh + hl + lh) -> ~2^-21 relative. XOR-swizzled LDS (16B granules).
// EPI 0: plain fp32 store. EPI 1: C = acc + bias[col] + xres[row,col].
template <int EPI>
__global__ __launch_bounds__(256) void gemm_f16s(
    const float* __restrict__ A, const f16* __restrict__ Bth,
    const f16* __restrict__ Btl, float* __restrict__ C, int M, int N, int K,
    const float* __restrict__ bias, const float* __restrict__ xres) {
  __shared__ f16 Ah[128 * 64];
  __shared__ f16 Al[128 * 64];
  __shared__ f16 Bh[128 * 64];
  __shared__ f16 Bl[128 * 64];
  const int tid = threadIdx.x;
  const int lane = tid & 63, wv = tid >> 6;
  const int wr = wv >> 1, wc = wv & 1;
  const int lm = lane & 15, lq = lane >> 4;
  const int m0 = blockIdx.y * 128, n0 = blockIdx.x * 128;
  f32x4 acc[4][4];
  const f32x4 z4 = {0.f, 0.f, 0.f, 0.f};
#pragma unroll
  for (int i = 0; i < 4; i++)
#pragma unroll
    for (int j = 0; j < 4; j++) acc[i][j] = z4;

  for (int k0 = 0; k0 < K; k0 += 64) {
    __syncthreads();
#pragma unroll
    for (int i = 0; i < 4; i++) {
      const int s = tid + i * 256;
      const int r = s >> 3, g = s & 7;
      float av[8];
      *(float4*)&av[0] = *(const float4*)(A + (size_t)(m0 + r) * K + k0 + g * 8);
      *(float4*)&av[4] =
          *(const float4*)(A + (size_t)(m0 + r) * K + k0 + g * 8 + 4);
      f16x8 hh, ll;
      split8(av, hh, ll);
      const int sw = r * 64 + ((g ^ (r & 7)) << 3);
      *(f16x8*)(&Ah[sw]) = hh;
      *(f16x8*)(&Al[sw]) = ll;
      *(f16x8*)(&Bh[sw]) = *(const f16x8*)(Bth + (size_t)(n0 + r) * K + k0 + g * 8);
      *(f16x8*)(&Bl[sw]) = *(const f16x8*)(Btl + (size_t)(n0 + r) * K + k0 + g * 8);
    }
    __syncthreads();
#pragma unroll
    for (int kx = 0; kx < 8; kx += 4) {
      f16x8 afh[4], afl[4], bfh[4], bfl[4];
#pragma unroll
      for (int i = 0; i < 4; i++) {
        const int ra = wr * 64 + i * 16 + lm;
        const int aw = ra * 64 + (((ra & 7) ^ (kx + lq)) << 3);
        afh[i] = *(const f16x8*)(&Ah[aw]);
        afl[i] = *(const f16x8*)(&Al[aw]);
        const int rb = wc * 64 + i * 16 + lm;
        const int bw = rb * 64 + (((rb & 7) ^ (kx + lq)) << 3);
        bfh[i] = *(const f16x8*)(&Bh[bw]);
        bfl[i] = *(const f16x8*)(&Bl[bw]);
      }
#pragma unroll
      for (int i = 0; i < 4; i++)
#pragma unroll
        for (int j = 0; j < 4; j++) {
          acc[i][j] = mfma_h(afh[i], bfh[j], acc[i][j]);
          acc[i][j] = mfma_h(afh[i], bfl[j], acc[i][j]);
          acc[i][j] = mfma_h(afl[i], bfh[j], acc[i][j]);
        }
    }
  }
#pragma unroll
  for (int i = 0; i < 4; i++)
#pragma unroll
    for (int r = 0; r < 4; r++) {
      const size_t row = m0 + wr * 64 + i * 16 + lq * 4 + r;
#pragma unroll
      for (int j = 0; j < 4; j++) {
        const int col = n0 + wc * 64 + j * 16 + lm;
        float v = acc[i][j][r];
        if (EPI == 1) v += bias[col] + xres[row * N + col];
        C[row * N + col] = v;
      }
    }
}

// -------------------------------------------------- f16-split flash attention
// block = (qtile 64, head, local-batch of quarter); 4 waves x 16 q-rows.
// All matmuls f16-split MFMA (3x), softmax fp32. LDS 48 KB -> 3 blocks/CU.
__global__ __launch_bounds__(256) void attn_f16s(const float* __restrict__ qkvf,
                                                 float* __restrict__ o,
                                                 int qb) {
  __shared__ f16 Kh[64 * 64];
  __shared__ f16 Kl[64 * 64];
  __shared__ f16 Vh[64 * 64];
  __shared__ f16 Vl[64 * 64];
  __shared__ f16 Ph[4 * 16 * 64];
  __shared__ f16 Pl[4 * 16 * 64];
  const int bz = blockIdx.z, h = blockIdx.y, qt = blockIdx.x;
  const int tid = threadIdx.x, wv = tid >> 6, lane = tid & 63;
  const int lm = lane & 15, lq = lane >> 4;

  // Q fragments (A-layout): rows wv*16+lm, k = frag*32 + lq*8 .. +8
  f16x8 qh[2], ql[2];
  {
    const size_t qbase =
        (size_t)(bz * 1024 + qt * 64 + wv * 16 + lm) * 2304 + h * 64;
#pragma unroll
    for (int f = 0; f < 2; f++) {
      float v[8];
      *(float4*)&v[0] = *(const float4*)(qkvf + qbase + f * 32 + lq * 8);
      *(float4*)&v[4] = *(const float4*)(qkvf + qbase + f * 32 + lq * 8 + 4);
      split8(v, qh[f], ql[f]);
    }
  }
  const f32x4 z4 = {0.f, 0.f, 0.f, 0.f};
  f32x4 oacc[4];
#pragma unroll
  for (int jb = 0; jb < 4; jb++) oacc[jb] = z4;
  float mrun[4], lrun[4];
#pragma unroll
  for (int r = 0; r < 4; r++) {
    mrun[r] = -1e30f;
    lrun[r] = 0.f;
  }
  const int vd = tid & 63;
  const int vkg = tid >> 6;
  f16* pwh = &Ph[wv * 16 * 64];
  f16* pwl = &Pl[wv * 16 * 64];

  for (int kt = 0; kt < 16; kt++) {
    __syncthreads();
    // stage K tile (64 keys x 64 dims) hi/lo, swizzled
#pragma unroll
    for (int i = 0; i < 2; i++) {
      const int s2 = tid + i * 256;
      const int r = s2 >> 3, g = s2 & 7;
      const size_t kb =
          (size_t)(bz * 1024 + kt * 64 + r) * 2304 + 768 + h * 64 + g * 8;
      float v[8];
      *(float4*)&v[0] = *(const float4*)(qkvf + kb);
      *(float4*)&v[4] = *(const float4*)(qkvf + kb + 4);
      f16x8 hh, ll;
      split8(v, hh, ll);
      const int sw = r * 64 + ((g ^ (r & 7)) << 3);
      *(f16x8*)(&Kh[sw]) = hh;
      *(f16x8*)(&Kl[sw]) = ll;
    }
    // stage V transposed: Vt[dim][key] hi/lo
#pragma unroll
    for (int sseg = 0; sseg < 2; sseg++) {
      const int k0v = vkg * 16 + sseg * 8;
      float v[8];
#pragma unroll
      for (int j = 0; j < 8; j++)
        v[j] = qkvf[(size_t)(bz * 1024 + kt * 64 + k0v + j) * 2304 + 1536 +
                    h * 64 + vd];
      f16x8 hh, ll;
      split8(v, hh, ll);
      const int g = k0v >> 3;
      const int sw = vd * 64 + ((g ^ (vd & 7)) << 3);
      *(f16x8*)(&Vh[sw]) = hh;
      *(f16x8*)(&Vl[sw]) = ll;
    }
    __syncthreads();

    // S = Q K^T (16 q-rows x 64 keys), f16-split
    f32x4 sa[4];
#pragma unroll
    for (int j = 0; j < 4; j++) sa[j] = z4;
#pragma unroll
    for (int kx = 0; kx < 8; kx += 4) {
      const f16x8 ah = qh[kx >> 2], al = ql[kx >> 2];
#pragma unroll
      for (int j = 0; j < 4; j++) {
        const int rb = j * 16 + lm;
        const int bw = rb * 64 + (((rb & 7) ^ (kx + lq)) << 3);
        const f16x8 bh = *(const f16x8*)(&Kh[bw]);
        const f16x8 bl = *(const f16x8*)(&Kl[bw]);
        sa[j] = mfma_h(ah, bh, sa[j]);
        sa[j] = mfma_h(ah, bl, sa[j]);
        sa[j] = mfma_h(al, bh, sa[j]);
      }
    }
#pragma unroll
    for (int j = 0; j < 4; j++)
#pragma unroll
      for (int r = 0; r < 4; r++) sa[j][r] *= 0.125f;  // Dh^-0.5

    // online softmax per q-row (quad shuffle)
#pragma unroll
    for (int r = 0; r < 4; r++) {
      float mx = fmaxf(fmaxf(sa[0][r], sa[1][r]), fmaxf(sa[2][r], sa[3][r]));
      mx = fmaxf(mx, __shfl_xor(mx, 1));
      mx = fmaxf(mx, __shfl_xor(mx, 2));
      mx = fmaxf(mx, __shfl_xor(mx, 4));
      mx = fmaxf(mx, __shfl_xor(mx, 8));
      const float mnew = fmaxf(mrun[r], mx);
      const float alpha = expf(mrun[r] - mnew);
      float ps = 0.f;
#pragma unroll
      for (int j = 0; j < 4; j++) {
        const float p = expf(sa[j][r] - mnew);
        sa[j][r] = p;
        ps += p;
      }
      ps += __shfl_xor(ps, 1);
      ps += __shfl_xor(ps, 2);
      ps += __shfl_xor(ps, 4);
      ps += __shfl_xor(ps, 8);
      lrun[r] = lrun[r] * alpha + ps;
      mrun[r] = mnew;
#pragma unroll
      for (int jb = 0; jb < 4; jb++) oacc[jb][r] *= alpha;
    }

    // P: C-layout -> per-wave LDS (A-layout roundtrip), split hi/lo
#pragma unroll
    for (int j = 0; j < 4; j++)
#pragma unroll
      for (int r = 0; r < 4; r++) {
        const int qr = lq * 4 + r;
        const int key = j * 16 + lm;
        const int ad = qr * 64 + (((qr & 7) ^ (key >> 3)) << 3) + (key & 7);
        const float p = sa[j][r];
        const f16 ph = (f16)p;
        pwh[ad] = ph;
        pwl[ad] = (f16)(p - (float)ph);
      }
    // O += P V, f16-split
#pragma unroll
    for (int kx2 = 0; kx2 < 8; kx2 += 4) {
      const int pw = lm * 64 + (((lm & 7) ^ (kx2 + lq)) << 3);
      const f16x8 pah = *(const f16x8*)(&pwh[pw]);
      const f16x8 pal = *(const f16x8*)(&pwl[pw]);
#pragma unroll
      for (int jb = 0; jb < 4; jb++) {
        const int rb = jb * 16 + lm;
        const int vw = rb * 64 + (((rb & 7) ^ (kx2 + lq)) << 3);
        const f16x8 vh = *(const f16x8*)(&Vh[vw]);
        const f16x8 vl = *(const f16x8*)(&Vl[vw]);
        oacc[jb] = mfma_h(pah, vh, oacc[jb]);
        oacc[jb] = mfma_h(pah, vl, oacc[jb]);
        oacc[jb] = mfma_h(pal, vh, oacc[jb]);
      }
    }
  }
  const int gtok = (qb * 4 + bz) * 1024 + qt * 64;
#pragma unroll
  for (int r = 0; r < 4; r++) {
    const float inv = 1.f / lrun[r];
    const size_t row = (size_t)gtok + wv * 16 + lq * 4 + r;
#pragma unroll
    for (int jb = 0; jb < 4; jb++) {
      const int col = h * 64 + jb * 16 + lm;
      o[row * CDIM + col] = oacc[jb][r] * inv;
    }
  }
}

// -------------------------------------------------- bf16 expert GEMM (MODE 2)
__global__ __launch_bounds__(256) void gemm_expert(
    const u16* __restrict__ A, const u16* __restrict__ Bt,
    float* __restrict__ C, int N, int K, const float* __restrict__ bias,
    const int* __restrict__ counts, const int* __restrict__ tokList,
    const float* __restrict__ wgtList) {
  __shared__ u16 As[128 * 64];
  __shared__ u16 Bs[128 * 64];
  const int tid = threadIdx.x;
  const int lane = tid & 63, wv = tid >> 6;
  const int wr = wv >> 1, wc = wv & 1;
  const int lm = lane & 15, lq = lane >> 4;
  const int m0 = blockIdx.y * 128, n0 = blockIdx.x * 128;
  const int e = blockIdx.z;
  const int cnt = counts[e];
  if (m0 >= cnt) return;
  const u16* Bte = Bt + (size_t)e * N * K;
  const int* tokl = tokList + e * TOKENS;
  const float* wl = wgtList + e * TOKENS;
  const float* biasE = bias + e * N;
  f32x4 acc[4][4];
  const f32x4 z4 = {0.f, 0.f, 0.f, 0.f};
#pragma unroll
  for (int i = 0; i < 4; i++)
#pragma unroll
    for (int j = 0; j < 4; j++) acc[i][j] = z4;

  for (int k0 = 0; k0 < K; k0 += 64) {
    __syncthreads();
#pragma unroll
    for (int i = 0; i < 4; i++) {
      const int s = tid + i * 256;
      const int r = s >> 3, g = s & 7;
      u32x4 av;
      const int row = m0 + r;
      if (row < cnt) {
        av = *(const u32x4*)(A + (size_t)tokl[row] * K + k0 + g * 8);
      } else {
        av = (u32x4){0u, 0u, 0u, 0u};
      }
      *(u32x4*)(&As[r * 64 + ((g ^ (r & 7)) << 3)]) = av;
      const u32x4 bv = *(const u32x4*)(Bte + (size_t)(n0 + r) * K + k0 + g * 8);
      *(u32x4*)(&Bs[r * 64 + ((g ^ (r & 7)) << 3)]) = bv;
    }
    __syncthreads();
#pragma unroll
    for (int kx = 0; kx < 8; kx += 4) {
      bf16x8 af[4], bfv[4];
#pragma unroll
      for (int i = 0; i < 4; i++) {
        const int ra = wr * 64 + i * 16 + lm;
        af[i] = *(const bf16x8*)(&As[ra * 64 + (((ra & 7) ^ (kx + lq)) << 3)]);
        const int rb = wc * 64 + i * 16 + lm;
        bfv[i] = *(const bf16x8*)(&Bs[rb * 64 + (((rb & 7) ^ (kx + lq)) << 3)]);
      }
#pragma unroll
      for (int i = 0; i < 4; i++)
#pragma unroll
        for (int j = 0; j < 4; j++)
          acc[i][j] = mfma_bf(af[i], bfv[j], acc[i][j]);
    }
  }
#pragma unroll
  for (int i = 0; i < 4; i++)
#pragma unroll
    for (int r = 0; r < 4; r++) {
      const int rowi = m0 + wr * 64 + i * 16 + lq * 4 + r;
      if (rowi < cnt) {
        const int tok = tokl[rowi];
        const float w = wl[rowi];
#pragma unroll
        for (int j = 0; j < 4; j++) {
          const int col = n0 + wc * 64 + j * 16 + lm;
          atomicAdd(&C[(size_t)tok * N + col], (acc[i][j][r] + biasE[col]) * w);
        }
      }
    }
}

// -------------------------------------------------- router (all fp32)
__global__ __launch_bounds__(256) void router_kernel(
    const float* __restrict__ x2, const float* __restrict__ g2,
    const float* __restrict__ b2, const float* __restrict__ rw,
    const float* __restrict__ rb, const float* __restrict__ rlng,
    const float* __restrict__ rlnb, const float* __restrict__ noise,
    int* __restrict__ eidx, float* __restrict__ ewgt) {
  const int token = blockIdx.x * 4 + (threadIdx.x >> 6);
  const int lane = threadIdx.x & 63;
  const size_t base = (size_t)token * CDIM;
  float v[12];
  float s = 0.f, ss = 0.f;
#pragma unroll
  for (int j = 0; j < 12; j++) {
    const int idx = lane + j * 64;
    v[j] = x2[base + idx];
    s += v[j];
    ss += v[j] * v[j];
  }
#pragma unroll
  for (int m = 1; m < 64; m <<= 1) {
    s += __shfl_xor(s, m);
    ss += __shfl_xor(ss, m);
  }
  const float mean = s * (1.f / CDIM);
  const float var = ss * (1.f / CDIM) - mean * mean;
  const float rs = rsqrtf(var + 1e-5f);

  float acc[8];
#pragma unroll
  for (int e = 0; e < 8; e++) acc[e] = 0.f;
#pragma unroll
  for (int j = 0; j < 12; j++) {
    const int d = lane + j * 64;
    const float hv = (v[j] - mean) * rs * g2[d] + b2[d];
    const f32x4 w0v = *(const f32x4*)(rw + (size_t)d * 8);
    const f32x4 w1v = *(const f32x4*)(rw + (size_t)d * 8 + 4);
#pragma unroll
    for (int e = 0; e < 4; e++) {
      acc[e] += hv * w0v[e];
      acc[e + 4] += hv * w1v[e];
    }
  }
#pragma unroll
  for (int m = 1; m < 64; m <<= 1)
#pragma unroll
    for (int e = 0; e < 8; e++) acc[e] += __shfl_xor(acc[e], m);

  float y[8];
  float emean = 0.f;
#pragma unroll
  for (int e = 0; e < 8; e++) {
    y[e] = acc[e] + rb[e];
    emean += y[e];
  }
  emean *= 0.125f;
  float evar = 0.f;
#pragma unroll
  for (int e = 0; e < 8; e++) {
    const float d = y[e] - emean;
    evar += d * d;
  }
  evar *= 0.125f;
  const float ers = rsqrtf(evar + 1e-5f);
  float lg[8];
  float mx = -1e30f;
#pragma unroll
  for (int e = 0; e < 8; e++) {
    lg[e] = (y[e] - emean) * ers * rlng[e] + rlnb[e];
    mx = fmaxf(mx, lg[e]);
  }
  float se = 0.f;
#pragma unroll
  for (int e = 0; e < 8; e++) {
    lg[e] = expf(lg[e] - mx);
    se += lg[e];
  }
  const float inv = 1.f / se;
  float r2[8];
#pragma unroll
  for (int e = 0; e < 8; e++)
    r2[e] = lg[e] * inv + noise[(size_t)token * 8 + e] * 0.125f;

  int e0 = 0;
  float v0 = r2[0];
#pragma unroll
  for (int e = 1; e < 8; e++)
    if (r2[e] > v0) {
      v0 = r2[e];
      e0 = e;
    }
  int e1 = -1;
  float v1 = -1e30f;
#pragma unroll
  for (int e = 0; e < 8; e++)
    if (e != e0 && r2[e] > v1) {
      v1 = r2[e];
      e1 = e;
    }
  const float w0 = 1.f / (1.f + expf(v1 - v0));
  if (lane == 0) {
    eidx[token * 2] = e0;
    eidx[token * 2 + 1] = e1;
    ewgt[token * 2] = w0;
    ewgt[token * 2 + 1] = 1.f - w0;
  }
}

// -------------------------------------------------- lists
__global__ __launch_bounds__(256) void build_lists(
    const int* __restrict__ eidx, const float* __restrict__ ewgt,
    int* __restrict__ counts, int* __restrict__ tokL,
    float* __restrict__ wgtL) {
  const int e = blockIdx.x;
  __shared__ int cnt;
  if (threadIdx.x == 0) cnt = 0;
  __syncthreads();
  const int lane = threadIdx.x & 63;
  for (int t = threadIdx.x; t < TOKENS; t += 256) {
#pragma unroll
    for (int k = 0; k < 2; k++) {
      const bool match = (eidx[t * 2 + k] == e);
      const unsigned long long mb = __ballot(match);
      if (mb) {
        const int leader = __ffsll((unsigned long long)mb) - 1;
        int base = 0;
        if (lane == leader) base = atomicAdd(&cnt, __popcll(mb));
        base = __shfl(base, leader);
        if (match) {
          const int rank = __popcll(mb & ((1ull << lane) - 1ull));
          tokL[e * TOKENS + base + rank] = t;
          wgtL[e * TOKENS + base + rank] = ewgt[t * 2 + k];
        }
      }
    }
  }
  __syncthreads();
  if (threadIdx.x == 0) counts[e] = cnt;
}

// -------------------------------------------------- copy
__global__ __launch_bounds__(256) void copy_f32(const float* __restrict__ in,
                                                float* __restrict__ out) {
  const int i = (blockIdx.x * 256 + threadIdx.x) * 4;
  *(float4*)(out + i) = *(const float4*)(in + i);
}

// -------------------------------------------------- launch
extern "C" void kernel_launch(void* const* d_in, const int* in_sizes, int n_in,
                              void* d_out, int out_size, void* d_ws,
                              size_t ws_size, hipStream_t stream) {
  const float* x = (const float*)d_in[0];
  const float* noise = (const float*)d_in[1];
  const float* ln1_g = (const float*)d_in[2];
  const float* ln1_b = (const float*)d_in[3];
  const float* qkv_w = (const float*)d_in[4];
  const float* proj_w = (const float*)d_in[5];
  const float* proj_b = (const float*)d_in[6];
  const float* ln2_g = (const float*)d_in[7];
  const float* ln2_b = (const float*)d_in[8];
  const float* route_w = (const float*)d_in[9];
  const float* route_b = (const float*)d_in[10];
  const float* rln_g = (const float*)d_in[11];
  const float* rln_b = (const float*)d_in[12];
  const float* expert_w = (const float*)d_in[13];
  const float* expert_b = (const float*)d_in[14];

  char* ws = (char*)d_ws;
  // [0, 50331648)            x2f fp32 (residual + accumulation target)
  // [50331648, 88080384)     qkvf fp32 quarter (4096 x 2304); post-attn this
  //                          region is reused for exp_wt + h2 + lists
  float* x2f = (float*)(ws);
  float* qkvf = (float*)(ws + 50331648);
  u16* exp_wt = (u16*)(ws + 50331648);    // 9437184 (post-attn)
  u16* h2 = (u16*)(ws + 59768832);        // 25165824 (post-attn)
  int* counts = (int*)(ws + 84934656);    // 256
  int* eidx = (int*)(ws + 84934912);      // 131072
  float* ewgt = (float*)(ws + 85065984);  // 131072
  int* tokL = (int*)(ws + 85197056);      // 524288
  float* wgtL = (float*)(ws + 85721344);  // 524288
  // weight f16 planes (persist whole launch; disjoint from qkvf region)
  f16* qkvw_h = (f16*)(ws + 88080384);    // 3538944
  f16* qkvw_l = (f16*)(ws + 91619328);    // 3538944
  f16* projw_h = (f16*)(ws + 95158272);   // 1179648
  f16* projw_l = (f16*)(ws + 96337920);   // 1179648  -> end 97517568
  // h1f (post-LN1) and attention output ping-pong through d_out (fp32)
  float* h1f = (float*)d_out;

  const dim3 blk(256);
  transpose_split_f16<<<dim3(36, 12), blk, 0, stream>>>(qkv_w, qkvw_h, qkvw_l,
                                                        768, 2304);
  transpose_split_f16<<<dim3(12, 12), blk, 0, stream>>>(proj_w, projw_h,
                                                        projw_l, 768, 768);
  ln_rows<false><<<dim3(4096), blk, 0, stream>>>(x, ln1_g, ln1_b, h1f);
  for (int q = 0; q < 4; q++) {
    gemm_f16s<0><<<dim3(18, 32), blk, 0, stream>>>(
        h1f + (size_t)q * 4096 * 768, qkvw_h, qkvw_l, qkvf, 4096, 2304, 768,
        nullptr, nullptr);
    attn_f16s<<<dim3(16, 12, 4), blk, 0, stream>>>(qkvf, h1f, q);
  }
  gemm_f16s<1><<<dim3(6, 128), blk, 0, stream>>>(h1f, projw_h, projw_l, x2f,
                                                 16384, 768, 768, proj_b, x);
  ln_rows<true><<<dim3(4096), blk, 0, stream>>>(x2f, ln2_g, ln2_b, h2);
  transpose_f32_bf16<<<dim3(12, 12, 8), blk, 0, stream>>>(expert_w, exp_wt,
                                                          768, 768);
  router_kernel<<<dim3(4096), blk, 0, stream>>>(x2f, ln2_g, ln2_b, route_w,
                                                route_b, rln_g, rln_b, noise,
                                                eidx, ewgt);
  build_lists<<<dim3(8), blk, 0, stream>>>(eidx, ewgt, counts, tokL, wgtL);
  gemm_expert<<<dim3(6, 128, 8), blk, 0, stream>>>(
      h2, exp_wt, x2f, 768, 768, expert_b, counts, tokL, wgtL);
  copy_f32<<<dim3(12288), blk, 0, stream>>>(x2f, (float*)d_out);
}